// Round 12
// baseline (109.648 us; speedup 1.0000x reference)
//
#include <hip/hip_runtime.h>
#include <hip/hip_fp16.h>

#define NN 16384
#define DD 256
#define CAP 160        // per-row list capacity (deg ~ Poisson(64), max ~112)
#define NB 128         // sorter blocks
#define BK 64
#define LDAP 72        // padded LDS row stride in bf16 elems (144 B)
#define PLP 2099200    // plane stride in f16 elems: (16384+16)*128 (16 zero pad rows)

typedef __attribute__((ext_vector_type(8))) __bf16 bf16x8;
typedef __attribute__((ext_vector_type(8))) unsigned short u16x8;
typedef __attribute__((ext_vector_type(4))) float f32x4;

__device__ __forceinline__ unsigned short f2bn(float f) {
    __bf16 h = (__bf16)f;
    return __builtin_bit_cast(unsigned short, h);
}

// ---------------- K1 prep: 0..127 hist | 128..191 x->bf16 | 192..199 W->bf16 | 200 pad zero
__global__ __launch_bounds__(512) void k_prep(const int* __restrict__ ei,
                                              unsigned short* __restrict__ H,
                                              const float* __restrict__ x,
                                              const float* __restrict__ Wu,
                                              const float* __restrict__ Wa,
                                              unsigned short* __restrict__ xb,
                                              unsigned short* __restrict__ wb,
                                              __half* __restrict__ xab,
                                              int E, int epb) {
    const int b = blockIdx.x;
    const int t = threadIdx.x;

    if (b >= 128) {
        if (b < 192) {
            const int w = b - 128;
#pragma unroll
            for (int i = 0; i < 32; ++i) {
                const int f4 = w * 16384 + i * 512 + t;
                float4 v = *(const float4*)(x + (size_t)f4 * 4);
                ushort4 o;
                o.x = f2bn(v.x); o.y = f2bn(v.y); o.z = f2bn(v.z); o.w = f2bn(v.w);
                *(ushort4*)(xb + (size_t)f4 * 4) = o;
            }
        } else if (b < 200) {
            const int w = b - 192;
            const float* src = (w < 4) ? Wu : Wa;
            unsigned short* dst = wb + ((w < 4) ? 0 : 65536);
            const int c0 = (w & 3) * 4096;
#pragma unroll
            for (int i = 0; i < 8; ++i) {
                const int f4 = c0 + i * 512 + t;
                float4 v = *(const float4*)(src + (size_t)f4 * 4);
                ushort4 o;
                o.x = f2bn(v.x); o.y = f2bn(v.y); o.z = f2bn(v.z); o.w = f2bn(v.w);
                *(ushort4*)(dst + (size_t)f4 * 4) = o;
            }
        } else {
            uint4 z; z.x = 0u; z.y = 0u; z.z = 0u; z.w = 0u;
            ((uint4*)xab)[(size_t)(t >> 8) * (PLP / 8) + (NN * 128 / 8) + (t & 255)] = z;
        }
        return;
    }

    __shared__ unsigned int h[NN / 2];  // packed: 2 rows per u32
    for (int i = t; i < NN / 2; i += 512) h[i] = 0u;
    __syncthreads();

    const int e0 = b * epb;
    const int e1 = min(e0 + epb, E);
    for (int e = e0 + t; e < e1; e += 512) {
        const int s = ei[e];
        const int d = ei[E + e];
        atomicAdd(&h[s >> 1], 1u << ((s & 1) << 4));
        atomicAdd(&h[d >> 1], 1u << ((d & 1) << 4));
    }
    __syncthreads();

    unsigned short* Hb = H + (size_t)b * NN;
    for (int r = t; r < NN; r += 512)
        Hb[r] = (unsigned short)((h[r >> 1] >> ((r & 1) << 4)) & 0xffffu);
}

// ---------------- K2 scan: LDS-transposed prefix over NB blocks ----------------
// 128 blocks x 128 rows. Load H[bb][r0..r0+127] coalesced -> tile[bb][j];
// threads 0..127 scan over bb (coalesced LDS); store H2t[r][bb] coalesced.
__global__ __launch_bounds__(512) void k_scan(const unsigned short* __restrict__ H,
                                              unsigned short* __restrict__ H2t,
                                              unsigned int* __restrict__ cnt) {
    __shared__ unsigned short tile[128][136];  // rows 272 B (16B-aligned)
    const int t = threadIdx.x;
    const int r0 = blockIdx.x << 7;

#pragma unroll
    for (int i = 0; i < 4; ++i) {
        const int f = i * 512 + t;        // 0..2047
        const int bb = f >> 4, q = f & 15;
        const uint4 v = *(const uint4*)(H + (size_t)bb * NN + r0 + q * 8);
        *(uint4*)(&tile[bb][q * 8]) = v;
    }
    __syncthreads();

    if (t < 128) {
        unsigned int base = 0;
#pragma unroll 8
        for (int bb = 0; bb < 128; ++bb) {
            const unsigned int v = tile[bb][t];
            tile[bb][t] = (unsigned short)base;
            base += v;
        }
        cnt[r0 + t] = base;
    }
    __syncthreads();

#pragma unroll
    for (int i = 0; i < 4; ++i) {
        const int f = i * 512 + t;        // r-major uint4 id
        const int j = f >> 4, q = f & 15;
        u16x8 o;
#pragma unroll
        for (int k = 0; k < 8; ++k) o[k] = tile[q * 8 + k][j];
        *(u16x8*)(H2t + (size_t)(r0 + j) * 128 + q * 8) = o;
    }
}

// ---------------- K3: blocks 0..511 GEMM (128x128 tiles); 512..639 fill ------------
// colq 0,1: out = x@Wu^T + bu + ba ; colq 2,3: xab[plane colq-2] = f16(x@Wa^T)
__global__ __launch_bounds__(512) void k_gemm_fill(const unsigned short* __restrict__ xb,
                                                   const unsigned short* __restrict__ wb,
                                                   const float* __restrict__ bu,
                                                   const float* __restrict__ ba,
                                                   const int* __restrict__ ei,
                                                   const unsigned short* __restrict__ H2t,
                                                   unsigned short* __restrict__ list,
                                                   float* __restrict__ out,
                                                   __half* __restrict__ xab,
                                                   int E, int epb) {
    __shared__ __align__(16) unsigned short smem[2 * 128 * LDAP];  // 36864 B
    const int t = threadIdx.x;

    if (blockIdx.x >= 512) {
        // ---- fill: per-row lists via LDS running offsets (no global atomics) ----
        unsigned int* off = (unsigned int*)smem;  // 32 KiB
        const int b = blockIdx.x - 512;
        for (int i = t; i < NN / 2; i += 512) off[i] = 0u;
        __syncthreads();
        const int e0 = b * epb;
        const int e1 = min(e0 + epb, E);
        for (int e = e0 + t; e < e1; e += 512) {
            const int s = ei[e];
            const int d = ei[E + e];
            const int sh1 = (s & 1) << 4;
            const unsigned int o1 = atomicAdd(&off[s >> 1], 1u << sh1);
            const int p1 = (int)H2t[(size_t)s * 128 + b] + (int)((o1 >> sh1) & 0xffffu);
            if (p1 < CAP) list[(size_t)s * CAP + p1] = (unsigned short)d;
            const int sh2 = (d & 1) << 4;
            const unsigned int o2 = atomicAdd(&off[d >> 1], 1u << sh2);
            const int p2 = (int)H2t[(size_t)d * 128 + b] + (int)((o2 >> sh2) & 0xffffu);
            if (p2 < CAP) list[(size_t)d * CAP + p2] = (unsigned short)s;
        }
        return;
    }

    unsigned short* As = smem;
    unsigned short* Bs = smem + 128 * LDAP;

    const int lane = t & 63;
    const int wid = t >> 6;
    const int wr = wid >> 2;          // 0..1: 64-row half
    const int wc = wid & 3;           // 0..3: 32-col quarter
    const int rowp = blockIdx.x >> 2;
    const int colq = blockIdx.x & 3;  // 0,1 -> out cols; 2,3 -> xab plane 0,1
    const int row0 = rowp << 7;
    const unsigned short* Wsrc = wb + ((size_t)colq << 15);

    f32x4 acc[4][2] = {};

    for (int k0 = 0; k0 < DD; k0 += BK) {
        uint4 ra_[2], rb_[2];
#pragma unroll
        for (int i = 0; i < 2; ++i) {
            const int f = i * 512 + t;      // uint4 id over 128x64 tile
            const int r = f >> 3, s = f & 7;
            ra_[i] = *(const uint4*)(xb + (size_t)(row0 + r) * DD + k0 + s * 8);
            rb_[i] = *(const uint4*)(Wsrc + (size_t)r * DD + k0 + s * 8);
        }
        __syncthreads();
#pragma unroll
        for (int i = 0; i < 2; ++i) {
            const int f = i * 512 + t;
            const int r = f >> 3, s = f & 7;
            *(uint4*)(&As[r * LDAP + s * 8]) = ra_[i];
            *(uint4*)(&Bs[r * LDAP + s * 8]) = rb_[i];
        }
        __syncthreads();
#pragma unroll
        for (int kk = 0; kk < 2; ++kk) {
            bf16x8 av[4], bv[2];
#pragma unroll
            for (int f = 0; f < 4; ++f) {
                uint4 ra = *(const uint4*)(&As[(wr * 64 + f * 16 + (lane & 15)) * LDAP + kk * 32 + (lane >> 4) * 8]);
                av[f] = __builtin_bit_cast(bf16x8, ra);
            }
#pragma unroll
            for (int f = 0; f < 2; ++f) {
                uint4 rv = *(const uint4*)(&Bs[(wc * 32 + f * 16 + (lane & 15)) * LDAP + kk * 32 + (lane >> 4) * 8]);
                bv[f] = __builtin_bit_cast(bf16x8, rv);
            }
#pragma unroll
            for (int fm = 0; fm < 4; ++fm)
#pragma unroll
                for (int fn = 0; fn < 2; ++fn)
                    acc[fm][fn] = __builtin_amdgcn_mfma_f32_16x16x32_bf16(
                        av[fm], bv[fn], acc[fm][fn], 0, 0, 0);
        }
    }

    // epilogue: C/D layout col = lane&15, row = (lane>>4)*4 + i
    const int gr0 = row0 + wr * 64 + ((lane >> 4) << 2);
    const int lc0 = wc * 32 + (lane & 15);
    if (colq < 2) {
#pragma unroll
        for (int fn = 0; fn < 2; ++fn) {
            const int c = (colq << 7) + lc0 + fn * 16;
            const float bias = bu[c] + ba[c];
#pragma unroll
            for (int fm = 0; fm < 4; ++fm) {
                const int r = gr0 + fm * 16;
#pragma unroll
                for (int i = 0; i < 4; ++i)
                    out[(size_t)(r + i) * DD + c] = acc[fm][fn][i] + bias;
            }
        }
    } else {
        __half* xp = xab + (size_t)(colq - 2) * PLP;
#pragma unroll
        for (int fn = 0; fn < 2; ++fn) {
            const int c = lc0 + fn * 16;
#pragma unroll
            for (int fm = 0; fm < 4; ++fm) {
                const int r = gr0 + fm * 16;
#pragma unroll
                for (int i = 0; i < 4; ++i)
                    xp[(size_t)(r + i) * 128 + c] = __float2half(acc[fm][fn][i]);
            }
        }
    }
}

// ---------------- K4/K5: gather pass (per plane) ----------------
// 1 wave per row, 4 rows/block. Dedup: LDS-bitmap atomicOr; dups -> sentinel row NN.
#define ACC4(S, V) { \
    acc[S][0] = __hadd2(acc[S][0], __builtin_bit_cast(__half2, (V).x)); \
    acc[S][1] = __hadd2(acc[S][1], __builtin_bit_cast(__half2, (V).y)); \
    acc[S][2] = __hadd2(acc[S][2], __builtin_bit_cast(__half2, (V).z)); \
    acc[S][3] = __hadd2(acc[S][3], __builtin_bit_cast(__half2, (V).w)); }

__global__ __launch_bounds__(256) void k_gather(const unsigned int* __restrict__ cnt,
                                                const unsigned short* __restrict__ list,
                                                const __half* __restrict__ plane,
                                                float* __restrict__ out,
                                                int outoff) {
    __shared__ unsigned int bmw[4][512];      // per-wave 2 KiB bitmap
    __shared__ unsigned short lst[4][CAP];

    const int t = threadIdx.x;
    const int wid = t >> 6;
    const int lane = t & 63;
    const int row = (blockIdx.x << 2) + wid;

    uint4 z4; z4.x = 0u; z4.y = 0u; z4.z = 0u; z4.w = 0u;
    ((uint4*)&bmw[wid][0])[lane] = z4;
    ((uint4*)&bmw[wid][0])[64 + lane] = z4;

    const int m = min((int)cnt[row], CAP);
    const unsigned short* gl = list + (size_t)row * CAP;
    for (int i = lane; i < m; i += 64) {
        int idx = gl[i];
        const unsigned int bit = 1u << (idx & 31);
        const unsigned int old = atomicOr(&bmw[wid][idx >> 5], bit);
        if (old & bit) idx = NN;              // duplicate -> zero pad row
        lst[wid][i] = (unsigned short)idx;
    }

    const int lg = lane >> 4;      // neighbor-octet slot 0..3
    const int li = lane & 15;      // dim group: f16 dims li*8..li*8+7
    __half2 acc[4][4];
    const __half2 z2 = __float2half2_rn(0.0f);
#pragma unroll
    for (int s = 0; s < 4; ++s) { acc[s][0] = z2; acc[s][1] = z2; acc[s][2] = z2; acc[s][3] = z2; }

    int i = 0;
    for (; i + 32 <= m; i += 32) {
        const u16x8 e = *(const u16x8*)(&lst[wid][i + lg * 8]);  // 1 ds_read_b128
        uint4 v[8];
#pragma unroll
        for (int j = 0; j < 8; ++j)
            v[j] = *(const uint4*)(plane + ((size_t)e[j] << 7) + li * 8);
#pragma unroll
        for (int j = 0; j < 8; ++j) ACC4(j & 3, v[j]);
    }
    for (; i + 4 <= m; i += 4) {
        uint4 v = *(const uint4*)(plane + ((size_t)lst[wid][i + lg] << 7) + li * 8);
        ACC4(0, v);
    }
    if (i < m && lg < m - i) {
        uint4 v = *(const uint4*)(plane + ((size_t)lst[wid][i + lg] << 7) + li * 8);
        ACC4(1, v);
    }

#pragma unroll
    for (int k = 0; k < 4; ++k) {
        acc[0][k] = __hadd2(acc[0][k], __hadd2(acc[1][k], __hadd2(acc[2][k], acc[3][k])));
        int v = __builtin_bit_cast(int, acc[0][k]);
        v = __shfl_xor(v, 16, 64);
        acc[0][k] = __hadd2(acc[0][k], __builtin_bit_cast(__half2, v));
        v = __builtin_bit_cast(int, acc[0][k]);
        v = __shfl_xor(v, 32, 64);
        acc[0][k] = __hadd2(acc[0][k], __builtin_bit_cast(__half2, v));
    }

    if (lg == 0) {
        float4* po = (float4*)(out + (size_t)row * DD + outoff + li * 8);
        float4 o0 = po[0], o1 = po[1];
        float2 f;
        f = __half22float2(acc[0][0]); o0.x += f.x; o0.y += f.y;
        f = __half22float2(acc[0][1]); o0.z += f.x; o0.w += f.y;
        f = __half22float2(acc[0][2]); o1.x += f.x; o1.y += f.y;
        f = __half22float2(acc[0][3]); o1.z += f.x; o1.w += f.y;
        po[0] = o0; po[1] = o1;
    }
}

extern "C" void kernel_launch(void* const* d_in, const int* in_sizes, int n_in,
                              void* d_out, int out_size, void* d_ws, size_t ws_size,
                              hipStream_t stream) {
    const float* x  = (const float*)d_in[0];
    const int*   ei = (const int*)d_in[1];
    const float* Wu = (const float*)d_in[2];
    const float* bu = (const float*)d_in[3];
    const float* Wa = (const float*)d_in[4];
    const float* ba = (const float*)d_in[5];
    float* out = (float*)d_out;

    const int E = in_sizes[1] / 2;
    const int epb = (E + NB - 1) / NB;

    char* ws = (char*)d_ws;
    __half* xab = (__half*)ws;                               // 0: 2 planes x PLP f16 = 8.01 MiB
    unsigned short* wb = (unsigned short*)(ws + 8396800);    // 256 KiB bf16 [Wu;Wa]
    unsigned short* xb = (unsigned short*)(ws + 8658944);    // 8 MiB bf16 x
    unsigned short* H = (unsigned short*)(ws + 17047552);    // 4 MiB raw histograms [b][r]
    unsigned int* cnt = (unsigned int*)(ws + 21241856);      // 64 KiB
    unsigned short* list = (unsigned short*)(ws + 21307392); // 5 MiB
    unsigned short* H2t = (unsigned short*)(ws + 26550272);  // 4 MiB scanned bases [r][b]

    k_prep<<<201, 512, 0, stream>>>(ei, H, x, Wu, Wa, xb, wb, xab, E, epb);
    k_scan<<<NN / 128, 512, 0, stream>>>(H, H2t, cnt);
    k_gemm_fill<<<640, 512, 0, stream>>>(xb, wb, bu, ba, ei, H2t, list, out, xab, E, epb);
    k_gather<<<NN / 4, 256, 0, stream>>>(cnt, list, xab, out, 0);
    k_gather<<<NN / 4, 256, 0, stream>>>(cnt, list, xab + PLP, out, 128);
}

// Round 13
// 97.961 us; speedup vs baseline: 1.1193x; 1.1193x over previous
//
#include <hip/hip_runtime.h>
#include <hip/hip_fp16.h>

#define NN 16384
#define DD 256
#define CAP 160        // per-row list capacity (deg ~ Poisson(64), max ~112)
#define NB 128         // sorter blocks
#define BK 64
#define LDAP 72        // padded LDS row stride in bf16 elems (144 B)
#define PLP 2099200    // plane stride in f16 elems: (16384+16)*128 (16 zero pad rows)

typedef __attribute__((ext_vector_type(8))) __bf16 bf16x8;
typedef __attribute__((ext_vector_type(8))) unsigned short u16x8;
typedef __attribute__((ext_vector_type(4))) float f32x4;

__device__ __forceinline__ unsigned short f2bn(float f) {
    __bf16 h = (__bf16)f;
    return __builtin_bit_cast(unsigned short, h);
}

// ---- K1 prep: 0..127 coarse hist | 128..191 x->bf16 | 192..199 W->bf16 | 200 pad --
__global__ __launch_bounds__(512) void k_prep(const int* __restrict__ ei,
                                              unsigned int* __restrict__ Hc,
                                              const float* __restrict__ x,
                                              const float* __restrict__ Wu,
                                              const float* __restrict__ Wa,
                                              unsigned short* __restrict__ xb,
                                              unsigned short* __restrict__ wb,
                                              __half* __restrict__ xab,
                                              int E, int epb) {
    const int b = blockIdx.x;
    const int t = threadIdx.x;

    if (b >= 128) {
        if (b < 192) {
            const int w = b - 128;
#pragma unroll
            for (int i = 0; i < 32; ++i) {
                const int f4 = w * 16384 + i * 512 + t;
                float4 v = *(const float4*)(x + (size_t)f4 * 4);
                ushort4 o;
                o.x = f2bn(v.x); o.y = f2bn(v.y); o.z = f2bn(v.z); o.w = f2bn(v.w);
                *(ushort4*)(xb + (size_t)f4 * 4) = o;
            }
        } else if (b < 200) {
            const int w = b - 192;
            const float* src = (w < 4) ? Wu : Wa;
            unsigned short* dst = wb + ((w < 4) ? 0 : 65536);
            const int c0 = (w & 3) * 4096;
#pragma unroll
            for (int i = 0; i < 8; ++i) {
                const int f4 = c0 + i * 512 + t;
                float4 v = *(const float4*)(src + (size_t)f4 * 4);
                ushort4 o;
                o.x = f2bn(v.x); o.y = f2bn(v.y); o.z = f2bn(v.z); o.w = f2bn(v.w);
                *(ushort4*)(dst + (size_t)f4 * 4) = o;
            }
        } else {
            uint4 z; z.x = 0u; z.y = 0u; z.z = 0u; z.w = 0u;
            ((uint4*)xab)[(size_t)(t >> 8) * (PLP / 8) + (NN * 128 / 8) + (t & 255)] = z;
        }
        return;
    }

    __shared__ unsigned int hc[128];
    if (t < 128) hc[t] = 0u;
    __syncthreads();

    const int e0 = b * epb;
    const int e1 = min(e0 + epb, E);
    for (int e = e0 + t; e < e1; e += 512) {
        const int s = ei[e];
        const int d = ei[E + e];
        atomicAdd(&hc[s >> 7], 1u);
        atomicAdd(&hc[d >> 7], 1u);
    }
    __syncthreads();
    if (t < 128) Hc[b * 128 + t] = hc[t];
}

// ---- K2 scan1 (1 block): runOfs[b][k] = bstart[k] + prefix_b(Hc[.][k]) ------------
__global__ __launch_bounds__(512) void k_scan1(const unsigned int* __restrict__ Hc,
                                               unsigned int* __restrict__ runOfs,
                                               unsigned int* __restrict__ bstart) {
    __shared__ unsigned short h16[128 * 128];  // 32 KiB (per-(b,k) counts < 64K)
    __shared__ unsigned int tot[128];
    __shared__ unsigned int bs[129];
    const int t = threadIdx.x;

    for (int i = t; i < 128 * 128; i += 512) h16[i] = (unsigned short)Hc[i];
    __syncthreads();

    if (t < 128) {
        unsigned int s = 0;
#pragma unroll 8
        for (int b = 0; b < 128; ++b) {
            const unsigned int v = h16[b * 128 + t];
            h16[b * 128 + t] = (unsigned short)s;   // per-bucket prefix < 16K: fits u16
            s += v;
        }
        tot[t] = s;
    }
    __syncthreads();
    if (t == 0) {
        unsigned int s = 0;
        for (int k = 0; k < 128; ++k) { bs[k] = s; s += tot[k]; }
        bs[128] = s;
    }
    __syncthreads();

    for (int i = t; i < 128 * 128; i += 512)
        runOfs[i] = bs[i & 127] + (unsigned int)h16[i];
    if (t < 129) bstart[t] = bs[t];
}

// ---- K3: blocks 0..511 GEMM (128x128 tiles); 512..639 bucket-scatter fill1 --------
// colq 0,1: out = x@Wu^T + bu + ba ; colq 2,3: xab[plane colq-2] = f16(x@Wa^T)
__global__ __launch_bounds__(512) void k_gemm_fill1(const unsigned short* __restrict__ xb,
                                                    const unsigned short* __restrict__ wb,
                                                    const float* __restrict__ bu,
                                                    const float* __restrict__ ba,
                                                    const int* __restrict__ ei,
                                                    const unsigned int* __restrict__ runOfs,
                                                    unsigned int* __restrict__ edgebuf,
                                                    float* __restrict__ out,
                                                    __half* __restrict__ xab,
                                                    int E, int epb) {
    __shared__ __align__(16) unsigned short smem[2 * 128 * LDAP];  // 36864 B
    const int t = threadIdx.x;

    if (blockIdx.x >= 512) {
        // ---- fill1: append (row<<14)|nbr to coarse-bucket runs (dense writes) ----
        unsigned int* cur = (unsigned int*)smem;  // 128 cursors
        const int b = blockIdx.x - 512;
        if (t < 128) cur[t] = runOfs[b * 128 + t];
        __syncthreads();
        const int e0 = b * epb;
        const int e1 = min(e0 + epb, E);
        for (int e = e0 + t; e < e1; e += 512) {
            const unsigned int s = (unsigned int)ei[e];
            const unsigned int d = (unsigned int)ei[E + e];
            const unsigned int p1 = atomicAdd(&cur[s >> 7], 1u);
            edgebuf[p1] = (s << 14) | d;
            const unsigned int p2 = atomicAdd(&cur[d >> 7], 1u);
            edgebuf[p2] = (d << 14) | s;
        }
        return;
    }

    unsigned short* As = smem;
    unsigned short* Bs = smem + 128 * LDAP;

    const int lane = t & 63;
    const int wid = t >> 6;
    const int wr = wid >> 2;          // 0..1: 64-row half
    const int wc = wid & 3;           // 0..3: 32-col quarter
    const int rowp = blockIdx.x >> 2;
    const int colq = blockIdx.x & 3;  // 0,1 -> out cols; 2,3 -> xab plane 0,1
    const int row0 = rowp << 7;
    const unsigned short* Wsrc = wb + ((size_t)colq << 15);

    f32x4 acc[4][2] = {};

    for (int k0 = 0; k0 < DD; k0 += BK) {
        uint4 ra_[2], rb_[2];
#pragma unroll
        for (int i = 0; i < 2; ++i) {
            const int f = i * 512 + t;      // uint4 id over 128x64 tile
            const int r = f >> 3, s = f & 7;
            ra_[i] = *(const uint4*)(xb + (size_t)(row0 + r) * DD + k0 + s * 8);
            rb_[i] = *(const uint4*)(Wsrc + (size_t)r * DD + k0 + s * 8);
        }
        __syncthreads();
#pragma unroll
        for (int i = 0; i < 2; ++i) {
            const int f = i * 512 + t;
            const int r = f >> 3, s = f & 7;
            *(uint4*)(&As[r * LDAP + s * 8]) = ra_[i];
            *(uint4*)(&Bs[r * LDAP + s * 8]) = rb_[i];
        }
        __syncthreads();
#pragma unroll
        for (int kk = 0; kk < 2; ++kk) {
            bf16x8 av[4], bv[2];
#pragma unroll
            for (int f = 0; f < 4; ++f) {
                uint4 ra = *(const uint4*)(&As[(wr * 64 + f * 16 + (lane & 15)) * LDAP + kk * 32 + (lane >> 4) * 8]);
                av[f] = __builtin_bit_cast(bf16x8, ra);
            }
#pragma unroll
            for (int f = 0; f < 2; ++f) {
                uint4 rv = *(const uint4*)(&Bs[(wc * 32 + f * 16 + (lane & 15)) * LDAP + kk * 32 + (lane >> 4) * 8]);
                bv[f] = __builtin_bit_cast(bf16x8, rv);
            }
#pragma unroll
            for (int fm = 0; fm < 4; ++fm)
#pragma unroll
                for (int fn = 0; fn < 2; ++fn)
                    acc[fm][fn] = __builtin_amdgcn_mfma_f32_16x16x32_bf16(
                        av[fm], bv[fn], acc[fm][fn], 0, 0, 0);
        }
    }

    const int gr0 = row0 + wr * 64 + ((lane >> 4) << 2);
    const int lc0 = wc * 32 + (lane & 15);
    if (colq < 2) {
#pragma unroll
        for (int fn = 0; fn < 2; ++fn) {
            const int c = (colq << 7) + lc0 + fn * 16;
            const float bias = bu[c] + ba[c];
#pragma unroll
            for (int fm = 0; fm < 4; ++fm) {
                const int r = gr0 + fm * 16;
#pragma unroll
                for (int i = 0; i < 4; ++i)
                    out[(size_t)(r + i) * DD + c] = acc[fm][fn][i] + bias;
            }
        }
    } else {
        __half* xp = xab + (size_t)(colq - 2) * PLP;
#pragma unroll
        for (int fn = 0; fn < 2; ++fn) {
            const int c = lc0 + fn * 16;
#pragma unroll
            for (int fm = 0; fm < 4; ++fm) {
                const int r = gr0 + fm * 16;
#pragma unroll
                for (int i = 0; i < 4; ++i)
                    xp[(size_t)(r + i) * 128 + c] = __float2half(acc[fm][fn][i]);
            }
        }
    }
}

// ---- K4 fill2: one block per bucket; build 128 rows' lists in LDS, write coalesced -
__global__ __launch_bounds__(512) void k_fill2(const unsigned int* __restrict__ edgebuf,
                                               const unsigned int* __restrict__ bstart,
                                               unsigned short* __restrict__ list,
                                               unsigned int* __restrict__ cnt) {
    __shared__ unsigned short ll[128 * CAP];  // 40960 B
    __shared__ unsigned int cur[128];
    const int k = blockIdx.x;
    const int t = threadIdx.x;

    if (t < 128) cur[t] = 0u;
    __syncthreads();

    const unsigned int s0 = bstart[k], s1 = bstart[k + 1];
    for (unsigned int j = s0 + t; j < s1; j += 512) {
        const unsigned int e = edgebuf[j];
        const int lr = (int)((e >> 14) & 127u);
        const unsigned short nbr = (unsigned short)(e & 16383u);
        const unsigned int p = atomicAdd(&cur[lr], 1u);
        if (p < CAP) ll[lr * CAP + p] = nbr;
    }
    __syncthreads();

    if (t < 128) cnt[(k << 7) + t] = cur[t];
    unsigned short* lrow = list + (size_t)(k << 7) * CAP;
    for (int i = t; i < 128 * CAP / 8; i += 512)
        *(u16x8*)(lrow + i * 8) = *(const u16x8*)(ll + i * 8);
}

// ---- K5/K6: gather pass (per plane) -----------------------------------------------
// 1 wave per row, 4 rows/block. Dedup: LDS-bitmap atomicOr; dups -> sentinel row NN.
#define ACC4(S, V) { \
    acc[S][0] = __hadd2(acc[S][0], __builtin_bit_cast(__half2, (V).x)); \
    acc[S][1] = __hadd2(acc[S][1], __builtin_bit_cast(__half2, (V).y)); \
    acc[S][2] = __hadd2(acc[S][2], __builtin_bit_cast(__half2, (V).z)); \
    acc[S][3] = __hadd2(acc[S][3], __builtin_bit_cast(__half2, (V).w)); }

__global__ __launch_bounds__(256) void k_gather(const unsigned int* __restrict__ cnt,
                                                const unsigned short* __restrict__ list,
                                                const __half* __restrict__ plane,
                                                float* __restrict__ out,
                                                int outoff) {
    __shared__ unsigned int bmw[4][512];      // per-wave 2 KiB bitmap
    __shared__ unsigned short lst[4][CAP];

    const int t = threadIdx.x;
    const int wid = t >> 6;
    const int lane = t & 63;
    const int row = (blockIdx.x << 2) + wid;

    uint4 z4; z4.x = 0u; z4.y = 0u; z4.z = 0u; z4.w = 0u;
    ((uint4*)&bmw[wid][0])[lane] = z4;
    ((uint4*)&bmw[wid][0])[64 + lane] = z4;

    const int m = min((int)cnt[row], CAP);
    const unsigned short* gl = list + (size_t)row * CAP;
    for (int i = lane; i < m; i += 64) {
        int idx = gl[i];
        const unsigned int bit = 1u << (idx & 31);
        const unsigned int old = atomicOr(&bmw[wid][idx >> 5], bit);
        if (old & bit) idx = NN;              // duplicate -> zero pad row
        lst[wid][i] = (unsigned short)idx;
    }

    const int lg = lane >> 4;      // neighbor-octet slot 0..3
    const int li = lane & 15;      // dim group: f16 dims li*8..li*8+7
    __half2 acc[4][4];
    const __half2 z2 = __float2half2_rn(0.0f);
#pragma unroll
    for (int s = 0; s < 4; ++s) { acc[s][0] = z2; acc[s][1] = z2; acc[s][2] = z2; acc[s][3] = z2; }

    int i = 0;
    for (; i + 32 <= m; i += 32) {
        const u16x8 e = *(const u16x8*)(&lst[wid][i + lg * 8]);  // 1 ds_read_b128
        uint4 v[8];
#pragma unroll
        for (int j = 0; j < 8; ++j)
            v[j] = *(const uint4*)(plane + ((size_t)e[j] << 7) + li * 8);
#pragma unroll
        for (int j = 0; j < 8; ++j) ACC4(j & 3, v[j]);
    }
    for (; i + 4 <= m; i += 4) {
        uint4 v = *(const uint4*)(plane + ((size_t)lst[wid][i + lg] << 7) + li * 8);
        ACC4(0, v);
    }
    if (i < m && lg < m - i) {
        uint4 v = *(const uint4*)(plane + ((size_t)lst[wid][i + lg] << 7) + li * 8);
        ACC4(1, v);
    }

#pragma unroll
    for (int k = 0; k < 4; ++k) {
        acc[0][k] = __hadd2(acc[0][k], __hadd2(acc[1][k], __hadd2(acc[2][k], acc[3][k])));
        int v = __builtin_bit_cast(int, acc[0][k]);
        v = __shfl_xor(v, 16, 64);
        acc[0][k] = __hadd2(acc[0][k], __builtin_bit_cast(__half2, v));
        v = __builtin_bit_cast(int, acc[0][k]);
        v = __shfl_xor(v, 32, 64);
        acc[0][k] = __hadd2(acc[0][k], __builtin_bit_cast(__half2, v));
    }

    if (lg == 0) {
        float4* po = (float4*)(out + (size_t)row * DD + outoff + li * 8);
        float4 o0 = po[0], o1 = po[1];
        float2 f;
        f = __half22float2(acc[0][0]); o0.x += f.x; o0.y += f.y;
        f = __half22float2(acc[0][1]); o0.z += f.x; o0.w += f.y;
        f = __half22float2(acc[0][2]); o1.x += f.x; o1.y += f.y;
        f = __half22float2(acc[0][3]); o1.z += f.x; o1.w += f.y;
        po[0] = o0; po[1] = o1;
    }
}

extern "C" void kernel_launch(void* const* d_in, const int* in_sizes, int n_in,
                              void* d_out, int out_size, void* d_ws, size_t ws_size,
                              hipStream_t stream) {
    const float* x  = (const float*)d_in[0];
    const int*   ei = (const int*)d_in[1];
    const float* Wu = (const float*)d_in[2];
    const float* bu = (const float*)d_in[3];
    const float* Wa = (const float*)d_in[4];
    const float* ba = (const float*)d_in[5];
    float* out = (float*)d_out;

    const int E = in_sizes[1] / 2;
    const int epb = (E + NB - 1) / NB;

    char* ws = (char*)d_ws;
    __half* xab = (__half*)ws;                                // 0: 2 planes = 8.01 MiB
    unsigned short* wb = (unsigned short*)(ws + 8396800);     // 256 KiB bf16 [Wu;Wa]
    unsigned short* xb = (unsigned short*)(ws + 8658944);     // 8 MiB bf16 x
    unsigned int* Hc = (unsigned int*)(ws + 17047552);        // 64 KiB coarse hists
    unsigned int* runOfs = (unsigned int*)(ws + 17113088);    // 64 KiB run offsets
    unsigned int* bstart = (unsigned int*)(ws + 17178624);    // 1 KiB bucket starts
    unsigned int* edgebuf = (unsigned int*)(ws + 17179648);   // 4 MiB bucketed edges
    unsigned int* cnt = (unsigned int*)(ws + 21373952);       // 64 KiB
    unsigned short* list = (unsigned short*)(ws + 21439488);  // 5 MiB

    k_prep<<<201, 512, 0, stream>>>(ei, Hc, x, Wu, Wa, xb, wb, xab, E, epb);
    k_scan1<<<1, 512, 0, stream>>>(Hc, runOfs, bstart);
    k_gemm_fill1<<<640, 512, 0, stream>>>(xb, wb, bu, ba, ei, runOfs, edgebuf, out, xab, E, epb);
    k_fill2<<<NB, 512, 0, stream>>>(edgebuf, bstart, list, cnt);
    k_gather<<<NN / 4, 256, 0, stream>>>(cnt, list, xab, out, 0);
    k_gather<<<NN / 4, 256, 0, stream>>>(cnt, list, xab + PLP, out, 128);
}

// Round 14
// 95.608 us; speedup vs baseline: 1.1468x; 1.0246x over previous
//
#include <hip/hip_runtime.h>
#include <hip/hip_fp16.h>

#define NN 16384
#define DD 256
#define CAP 192        // per-row list capacity, padded to mult of 32 (deg ~ Poisson(64))
#define NB 128         // sorter blocks
#define BK 64
#define LDAP 72        // padded LDS row stride in bf16 elems (144 B)
#define PLP 2099200    // plane stride in f16 elems: (16384+16)*128 (16 zero pad rows)

typedef __attribute__((ext_vector_type(8))) __bf16 bf16x8;
typedef __attribute__((ext_vector_type(8))) unsigned short u16x8;
typedef __attribute__((ext_vector_type(4))) float f32x4;

__device__ __forceinline__ unsigned short f2bn(float f) {
    __bf16 h = (__bf16)f;
    return __builtin_bit_cast(unsigned short, h);
}

// ---- K1 prep: 0..127 coarse hist | 128..191 x->bf16 | 192..199 W->bf16 | 200 pad --
__global__ __launch_bounds__(512) void k_prep(const int* __restrict__ ei,
                                              unsigned int* __restrict__ Hc,
                                              const float* __restrict__ x,
                                              const float* __restrict__ Wu,
                                              const float* __restrict__ Wa,
                                              unsigned short* __restrict__ xb,
                                              unsigned short* __restrict__ wb,
                                              __half* __restrict__ xab,
                                              int E, int epb) {
    const int b = blockIdx.x;
    const int t = threadIdx.x;

    if (b >= 128) {
        if (b < 192) {
            const int w = b - 128;
#pragma unroll
            for (int i = 0; i < 32; ++i) {
                const int f4 = w * 16384 + i * 512 + t;
                float4 v = *(const float4*)(x + (size_t)f4 * 4);
                ushort4 o;
                o.x = f2bn(v.x); o.y = f2bn(v.y); o.z = f2bn(v.z); o.w = f2bn(v.w);
                *(ushort4*)(xb + (size_t)f4 * 4) = o;
            }
        } else if (b < 200) {
            const int w = b - 192;
            const float* src = (w < 4) ? Wu : Wa;
            unsigned short* dst = wb + ((w < 4) ? 0 : 65536);
            const int c0 = (w & 3) * 4096;
#pragma unroll
            for (int i = 0; i < 8; ++i) {
                const int f4 = c0 + i * 512 + t;
                float4 v = *(const float4*)(src + (size_t)f4 * 4);
                ushort4 o;
                o.x = f2bn(v.x); o.y = f2bn(v.y); o.z = f2bn(v.z); o.w = f2bn(v.w);
                *(ushort4*)(dst + (size_t)f4 * 4) = o;
            }
        } else {
            uint4 z; z.x = 0u; z.y = 0u; z.z = 0u; z.w = 0u;
            ((uint4*)xab)[(size_t)(t >> 8) * (PLP / 8) + (NN * 128 / 8) + (t & 255)] = z;
        }
        return;
    }

    __shared__ unsigned int hc[128];
    if (t < 128) hc[t] = 0u;
    __syncthreads();

    const int e0 = b * epb;
    const int e1 = min(e0 + epb, E);
    for (int e = e0 + t; e < e1; e += 512) {
        const int s = ei[e];
        const int d = ei[E + e];
        atomicAdd(&hc[s >> 7], 1u);
        atomicAdd(&hc[d >> 7], 1u);
    }
    __syncthreads();
    if (t < 128) Hc[b * 128 + t] = hc[t];
}

// ---- K2 scan1 (1 block): runOfs[b][k] = bstart[k] + prefix_b(Hc[.][k]) ------------
__global__ __launch_bounds__(512) void k_scan1(const unsigned int* __restrict__ Hc,
                                               unsigned int* __restrict__ runOfs,
                                               unsigned int* __restrict__ bstart) {
    __shared__ unsigned short h16[128 * 128];
    __shared__ unsigned int tot[128];
    __shared__ unsigned int bs[129];
    const int t = threadIdx.x;

    for (int i = t; i < 128 * 128; i += 512) h16[i] = (unsigned short)Hc[i];
    __syncthreads();

    if (t < 128) {
        unsigned int s = 0;
#pragma unroll 8
        for (int b = 0; b < 128; ++b) {
            const unsigned int v = h16[b * 128 + t];
            h16[b * 128 + t] = (unsigned short)s;
            s += v;
        }
        tot[t] = s;
    }
    __syncthreads();
    if (t == 0) {
        unsigned int s = 0;
        for (int k = 0; k < 128; ++k) { bs[k] = s; s += tot[k]; }
        bs[128] = s;
    }
    __syncthreads();

    for (int i = t; i < 128 * 128; i += 512)
        runOfs[i] = bs[i & 127] + (unsigned int)h16[i];
    if (t < 129) bstart[t] = bs[t];
}

// ---- K3: blocks 0..511 GEMM (128x128, XCD-swizzled); 512..639 bucket-scatter ------
// rowp = blk&127, colq = blk>>7: the 4 colq blocks of a row panel sit 128 apart
// -> same XCD (128%8==0) -> A panel fetched once from HBM, 3x L2-hit.
__global__ __launch_bounds__(512) void k_gemm_fill1(const unsigned short* __restrict__ xb,
                                                    const unsigned short* __restrict__ wb,
                                                    const float* __restrict__ bu,
                                                    const float* __restrict__ ba,
                                                    const int* __restrict__ ei,
                                                    const unsigned int* __restrict__ runOfs,
                                                    unsigned int* __restrict__ edgebuf,
                                                    float* __restrict__ out,
                                                    __half* __restrict__ xab,
                                                    int E, int epb) {
    __shared__ __align__(16) unsigned short smem[2 * 128 * LDAP];  // 36864 B
    const int t = threadIdx.x;

    if (blockIdx.x >= 512) {
        // ---- fill1: append (row<<14)|nbr to coarse-bucket runs (dense writes) ----
        unsigned int* cur = (unsigned int*)smem;
        const int b = blockIdx.x - 512;
        if (t < 128) cur[t] = runOfs[b * 128 + t];
        __syncthreads();
        const int e0 = b * epb;
        const int e1 = min(e0 + epb, E);
        for (int e = e0 + t; e < e1; e += 512) {
            const unsigned int s = (unsigned int)ei[e];
            const unsigned int d = (unsigned int)ei[E + e];
            const unsigned int p1 = atomicAdd(&cur[s >> 7], 1u);
            edgebuf[p1] = (s << 14) | d;
            const unsigned int p2 = atomicAdd(&cur[d >> 7], 1u);
            edgebuf[p2] = (d << 14) | s;
        }
        return;
    }

    unsigned short* As = smem;
    unsigned short* Bs = smem + 128 * LDAP;

    const int lane = t & 63;
    const int wid = t >> 6;
    const int wr = wid >> 2;
    const int wc = wid & 3;
    const int rowp = blockIdx.x & 127;   // XCD swizzle (see header comment)
    const int colq = blockIdx.x >> 7;
    const int row0 = rowp << 7;
    const unsigned short* Wsrc = wb + ((size_t)colq << 15);

    f32x4 acc[4][2] = {};

    for (int k0 = 0; k0 < DD; k0 += BK) {
        uint4 ra_[2], rb_[2];
#pragma unroll
        for (int i = 0; i < 2; ++i) {
            const int f = i * 512 + t;
            const int r = f >> 3, s = f & 7;
            ra_[i] = *(const uint4*)(xb + (size_t)(row0 + r) * DD + k0 + s * 8);
            rb_[i] = *(const uint4*)(Wsrc + (size_t)r * DD + k0 + s * 8);
        }
        __syncthreads();
#pragma unroll
        for (int i = 0; i < 2; ++i) {
            const int f = i * 512 + t;
            const int r = f >> 3, s = f & 7;
            *(uint4*)(&As[r * LDAP + s * 8]) = ra_[i];
            *(uint4*)(&Bs[r * LDAP + s * 8]) = rb_[i];
        }
        __syncthreads();
#pragma unroll
        for (int kk = 0; kk < 2; ++kk) {
            bf16x8 av[4], bv[2];
#pragma unroll
            for (int f = 0; f < 4; ++f) {
                uint4 ra = *(const uint4*)(&As[(wr * 64 + f * 16 + (lane & 15)) * LDAP + kk * 32 + (lane >> 4) * 8]);
                av[f] = __builtin_bit_cast(bf16x8, ra);
            }
#pragma unroll
            for (int f = 0; f < 2; ++f) {
                uint4 rv = *(const uint4*)(&Bs[(wc * 32 + f * 16 + (lane & 15)) * LDAP + kk * 32 + (lane >> 4) * 8]);
                bv[f] = __builtin_bit_cast(bf16x8, rv);
            }
#pragma unroll
            for (int fm = 0; fm < 4; ++fm)
#pragma unroll
                for (int fn = 0; fn < 2; ++fn)
                    acc[fm][fn] = __builtin_amdgcn_mfma_f32_16x16x32_bf16(
                        av[fm], bv[fn], acc[fm][fn], 0, 0, 0);
        }
    }

    const int gr0 = row0 + wr * 64 + ((lane >> 4) << 2);
    const int lc0 = wc * 32 + (lane & 15);
    if (colq < 2) {
#pragma unroll
        for (int fn = 0; fn < 2; ++fn) {
            const int c = (colq << 7) + lc0 + fn * 16;
            const float bias = bu[c] + ba[c];
#pragma unroll
            for (int fm = 0; fm < 4; ++fm) {
                const int r = gr0 + fm * 16;
#pragma unroll
                for (int i = 0; i < 4; ++i)
                    out[(size_t)(r + i) * DD + c] = acc[fm][fn][i] + bias;
            }
        }
    } else {
        __half* xp = xab + (size_t)(colq - 2) * PLP;
#pragma unroll
        for (int fn = 0; fn < 2; ++fn) {
            const int c = lc0 + fn * 16;
#pragma unroll
            for (int fm = 0; fm < 4; ++fm) {
                const int r = gr0 + fm * 16;
#pragma unroll
                for (int i = 0; i < 4; ++i)
                    xp[(size_t)(r + i) * 128 + c] = __float2half(acc[fm][fn][i]);
            }
        }
    }
}

// ---- K4 fill2: one block per bucket; lists built in LDS, SENTINEL-PADDED to x32 ----
__global__ __launch_bounds__(512) void k_fill2(const unsigned int* __restrict__ edgebuf,
                                               const unsigned int* __restrict__ bstart,
                                               unsigned short* __restrict__ list,
                                               unsigned int* __restrict__ cnt) {
    __shared__ unsigned short ll[128 * CAP];  // 49152 B
    __shared__ unsigned int cur[128];
    const int k = blockIdx.x;
    const int t = threadIdx.x;

    if (t < 128) cur[t] = 0u;
    {
        u16x8 s8;
#pragma unroll
        for (int j = 0; j < 8; ++j) s8[j] = (unsigned short)NN;   // sentinel
        for (int i = t; i < 128 * CAP / 8; i += 512) *(u16x8*)(ll + i * 8) = s8;
    }
    __syncthreads();

    const unsigned int s0 = bstart[k], s1 = bstart[k + 1];
    for (unsigned int j = s0 + t; j < s1; j += 512) {
        const unsigned int e = edgebuf[j];
        const int lr = (int)((e >> 14) & 127u);
        const unsigned short nbr = (unsigned short)(e & 16383u);
        const unsigned int p = atomicAdd(&cur[lr], 1u);
        if (p < CAP) ll[lr * CAP + p] = nbr;
    }
    __syncthreads();

    if (t < 128) cnt[(k << 7) + t] = min((cur[t] + 31u) & ~31u, (unsigned int)CAP);
    unsigned short* lrow = list + (size_t)(k << 7) * CAP;
    for (int i = t; i < 128 * CAP / 8; i += 512)
        *(u16x8*)(lrow + i * 8) = *(const u16x8*)(ll + i * 8);
}

// ---- K5/K6: gather pass (per plane) -----------------------------------------------
// 1 wave per row, 4 rows/block. cnt is a multiple of 32 -> only the depth-8 main
// loop runs (no shallow tails). Dedup: LDS bitmap; dups & pads -> sentinel row NN.
#define ACC4(S, V) { \
    acc[S][0] = __hadd2(acc[S][0], __builtin_bit_cast(__half2, (V).x)); \
    acc[S][1] = __hadd2(acc[S][1], __builtin_bit_cast(__half2, (V).y)); \
    acc[S][2] = __hadd2(acc[S][2], __builtin_bit_cast(__half2, (V).z)); \
    acc[S][3] = __hadd2(acc[S][3], __builtin_bit_cast(__half2, (V).w)); }

__global__ __launch_bounds__(256) void k_gather(const unsigned int* __restrict__ cnt,
                                                const unsigned short* __restrict__ list,
                                                const __half* __restrict__ plane,
                                                float* __restrict__ out,
                                                int outoff) {
    __shared__ unsigned int bmw[4][512];      // per-wave 2 KiB bitmap
    __shared__ unsigned short lst[4][CAP];

    const int t = threadIdx.x;
    const int wid = t >> 6;
    const int lane = t & 63;
    const int row = (blockIdx.x << 2) + wid;

    uint4 z4; z4.x = 0u; z4.y = 0u; z4.z = 0u; z4.w = 0u;
    ((uint4*)&bmw[wid][0])[lane] = z4;
    ((uint4*)&bmw[wid][0])[64 + lane] = z4;

    const int m = min((int)cnt[row], CAP);
    const unsigned short* gl = list + (size_t)row * CAP;
    for (int i = lane; i < m; i += 64) {
        int idx = gl[i];
        if (idx < NN) {
            const unsigned int bit = 1u << (idx & 31);
            const unsigned int old = atomicOr(&bmw[wid][idx >> 5], bit);
            if (old & bit) idx = NN;          // duplicate -> zero pad row
        }
        lst[wid][i] = (unsigned short)idx;
    }

    const int lg = lane >> 4;      // neighbor-octet slot 0..3
    const int li = lane & 15;      // dim group: f16 dims li*8..li*8+7
    __half2 acc[4][4];
    const __half2 z2 = __float2half2_rn(0.0f);
#pragma unroll
    for (int s = 0; s < 4; ++s) { acc[s][0] = z2; acc[s][1] = z2; acc[s][2] = z2; acc[s][3] = z2; }

    int i = 0;
    for (; i + 32 <= m; i += 32) {
        const u16x8 e = *(const u16x8*)(&lst[wid][i + lg * 8]);  // 1 ds_read_b128
        uint4 v[8];
#pragma unroll
        for (int j = 0; j < 8; ++j)
            v[j] = *(const uint4*)(plane + ((size_t)e[j] << 7) + li * 8);
#pragma unroll
        for (int j = 0; j < 8; ++j) ACC4(j & 3, v[j]);
    }
    // (cnt is padded to x32 -- tails below are defensive only)
    for (; i + 4 <= m; i += 4) {
        uint4 v = *(const uint4*)(plane + ((size_t)lst[wid][i + lg] << 7) + li * 8);
        ACC4(0, v);
    }
    if (i < m && lg < m - i) {
        uint4 v = *(const uint4*)(plane + ((size_t)lst[wid][i + lg] << 7) + li * 8);
        ACC4(1, v);
    }

#pragma unroll
    for (int k = 0; k < 4; ++k) {
        acc[0][k] = __hadd2(acc[0][k], __hadd2(acc[1][k], __hadd2(acc[2][k], acc[3][k])));
        int v = __builtin_bit_cast(int, acc[0][k]);
        v = __shfl_xor(v, 16, 64);
        acc[0][k] = __hadd2(acc[0][k], __builtin_bit_cast(__half2, v));
        v = __builtin_bit_cast(int, acc[0][k]);
        v = __shfl_xor(v, 32, 64);
        acc[0][k] = __hadd2(acc[0][k], __builtin_bit_cast(__half2, v));
    }

    if (lg == 0) {
        float4* po = (float4*)(out + (size_t)row * DD + outoff + li * 8);
        float4 o0 = po[0], o1 = po[1];
        float2 f;
        f = __half22float2(acc[0][0]); o0.x += f.x; o0.y += f.y;
        f = __half22float2(acc[0][1]); o0.z += f.x; o0.w += f.y;
        f = __half22float2(acc[0][2]); o1.x += f.x; o1.y += f.y;
        f = __half22float2(acc[0][3]); o1.z += f.x; o1.w += f.y;
        po[0] = o0; po[1] = o1;
    }
}

extern "C" void kernel_launch(void* const* d_in, const int* in_sizes, int n_in,
                              void* d_out, int out_size, void* d_ws, size_t ws_size,
                              hipStream_t stream) {
    const float* x  = (const float*)d_in[0];
    const int*   ei = (const int*)d_in[1];
    const float* Wu = (const float*)d_in[2];
    const float* bu = (const float*)d_in[3];
    const float* Wa = (const float*)d_in[4];
    const float* ba = (const float*)d_in[5];
    float* out = (float*)d_out;

    const int E = in_sizes[1] / 2;
    const int epb = (E + NB - 1) / NB;

    char* ws = (char*)d_ws;
    __half* xab = (__half*)ws;                                // 0: 2 planes = 8.01 MiB
    unsigned short* wb = (unsigned short*)(ws + 8396800);     // 256 KiB bf16 [Wu;Wa]
    unsigned short* xb = (unsigned short*)(ws + 8658944);     // 8 MiB bf16 x
    unsigned int* Hc = (unsigned int*)(ws + 17047552);        // 64 KiB coarse hists
    unsigned int* runOfs = (unsigned int*)(ws + 17113088);    // 64 KiB run offsets
    unsigned int* bstart = (unsigned int*)(ws + 17178624);    // 1 KiB bucket starts
    unsigned int* edgebuf = (unsigned int*)(ws + 17179648);   // 4 MiB bucketed edges
    unsigned int* cnt = (unsigned int*)(ws + 21373952);       // 64 KiB
    unsigned short* list = (unsigned short*)(ws + 21439488);  // 6 MiB (CAP=192)

    k_prep<<<201, 512, 0, stream>>>(ei, Hc, x, Wu, Wa, xb, wb, xab, E, epb);
    k_scan1<<<1, 512, 0, stream>>>(Hc, runOfs, bstart);
    k_gemm_fill1<<<640, 512, 0, stream>>>(xb, wb, bu, ba, ei, runOfs, edgebuf, out, xab, E, epb);
    k_fill2<<<NB, 512, 0, stream>>>(edgebuf, bstart, list, cnt);
    k_gather<<<NN / 4, 256, 0, stream>>>(cnt, list, xab, out, 0);
    k_gather<<<NN / 4, 256, 0, stream>>>(cnt, list, xab + PLP, out, 128);
}

// Round 15
// 92.426 us; speedup vs baseline: 1.1863x; 1.0344x over previous
//
#include <hip/hip_runtime.h>
#include <hip/hip_fp16.h>

#define NN 16384
#define DD 256
#define CAP 160        // per-row list capacity, padded to mult of 32 (deg ~ Poisson(64), max ~112)
#define NB 128         // sorter blocks
#define BK 64
#define LDAP 72        // padded LDS row stride in bf16 elems (144 B)
#define PLP 2099200    // xab plane stride in f16 elems: (16384+16)*128 (16 zero pad rows)
#define XUP 2097152    // xu plane stride in f16 elems: 16384*128

typedef __attribute__((ext_vector_type(8))) __bf16 bf16x8;
typedef __attribute__((ext_vector_type(8))) unsigned short u16x8;
typedef __attribute__((ext_vector_type(4))) float f32x4;

__device__ __forceinline__ unsigned short f2bn(float f) {
    __bf16 h = (__bf16)f;
    return __builtin_bit_cast(unsigned short, h);
}

// ---- K1 prep: 0..127 coarse hist | 128..191 x->bf16 | 192..199 W->bf16 | 200 pad --
__global__ __launch_bounds__(512) void k_prep(const int* __restrict__ ei,
                                              unsigned int* __restrict__ Hc,
                                              const float* __restrict__ x,
                                              const float* __restrict__ Wu,
                                              const float* __restrict__ Wa,
                                              unsigned short* __restrict__ xb,
                                              unsigned short* __restrict__ wb,
                                              __half* __restrict__ xab,
                                              int E, int epb) {
    const int b = blockIdx.x;
    const int t = threadIdx.x;

    if (b >= 128) {
        if (b < 192) {
            const int w = b - 128;
#pragma unroll
            for (int i = 0; i < 32; ++i) {
                const int f4 = w * 16384 + i * 512 + t;
                float4 v = *(const float4*)(x + (size_t)f4 * 4);
                ushort4 o;
                o.x = f2bn(v.x); o.y = f2bn(v.y); o.z = f2bn(v.z); o.w = f2bn(v.w);
                *(ushort4*)(xb + (size_t)f4 * 4) = o;
            }
        } else if (b < 200) {
            const int w = b - 192;
            const float* src = (w < 4) ? Wu : Wa;
            unsigned short* dst = wb + ((w < 4) ? 0 : 65536);
            const int c0 = (w & 3) * 4096;
#pragma unroll
            for (int i = 0; i < 8; ++i) {
                const int f4 = c0 + i * 512 + t;
                float4 v = *(const float4*)(src + (size_t)f4 * 4);
                ushort4 o;
                o.x = f2bn(v.x); o.y = f2bn(v.y); o.z = f2bn(v.z); o.w = f2bn(v.w);
                *(ushort4*)(dst + (size_t)f4 * 4) = o;
            }
        } else {
            // zero the 16 pad rows of each xab plane (sentinel target)
            uint4 z; z.x = 0u; z.y = 0u; z.z = 0u; z.w = 0u;
            ((uint4*)xab)[(size_t)(t >> 8) * (PLP / 8) + (NN * 128 / 8) + (t & 255)] = z;
        }
        return;
    }

    __shared__ unsigned int hc[128];
    if (t < 128) hc[t] = 0u;
    __syncthreads();

    const int e0 = b * epb;
    const int e1 = min(e0 + epb, E);
    for (int e = e0 + t; e < e1; e += 512) {
        const int s = ei[e];
        const int d = ei[E + e];
        atomicAdd(&hc[s >> 7], 1u);
        atomicAdd(&hc[d >> 7], 1u);
    }
    __syncthreads();
    if (t < 128) Hc[b * 128 + t] = hc[t];
}

// ---- K2 scan1 (1 block): runOfs[b][k] = bstart[k] + prefix_b(Hc[.][k]) ------------
__global__ __launch_bounds__(512) void k_scan1(const unsigned int* __restrict__ Hc,
                                               unsigned int* __restrict__ runOfs,
                                               unsigned int* __restrict__ bstart) {
    __shared__ unsigned short h16[128 * 128];
    __shared__ unsigned int tot[128];
    __shared__ unsigned int bs[129];
    const int t = threadIdx.x;

    for (int i = t; i < 128 * 128; i += 512) h16[i] = (unsigned short)Hc[i];
    __syncthreads();

    if (t < 128) {
        unsigned int s = 0;
#pragma unroll 8
        for (int b = 0; b < 128; ++b) {
            const unsigned int v = h16[b * 128 + t];
            h16[b * 128 + t] = (unsigned short)s;
            s += v;
        }
        tot[t] = s;
    }
    __syncthreads();
    if (t == 0) {
        unsigned int s = 0;
        for (int k = 0; k < 128; ++k) { bs[k] = s; s += tot[k]; }
        bs[128] = s;
    }
    __syncthreads();

    for (int i = t; i < 128 * 128; i += 512)
        runOfs[i] = bs[i & 127] + (unsigned int)h16[i];
    if (t < 129) bstart[t] = bs[t];
}

// ---- K3: blocks 0..511 GEMM (128x128, XCD-swizzled); 512..639 bucket-scatter ------
// colq 0,1: xu[plane colq]  = f16(x@Wu^T + bu + ba)   (update path, f16 planes)
// colq 2,3: xab[plane colq-2] = f16(x@Wa^T)            (aggregate operand)
__global__ __launch_bounds__(512) void k_gemm_fill1(const unsigned short* __restrict__ xb,
                                                    const unsigned short* __restrict__ wb,
                                                    const float* __restrict__ bu,
                                                    const float* __restrict__ ba,
                                                    const int* __restrict__ ei,
                                                    const unsigned int* __restrict__ runOfs,
                                                    unsigned int* __restrict__ edgebuf,
                                                    __half* __restrict__ xu,
                                                    __half* __restrict__ xab,
                                                    int E, int epb) {
    __shared__ __align__(16) unsigned short smem[2 * 128 * LDAP];  // 36864 B
    const int t = threadIdx.x;

    if (blockIdx.x >= 512) {
        // ---- fill1: append (row<<14)|nbr to coarse-bucket runs (dense writes) ----
        unsigned int* cur = (unsigned int*)smem;
        const int b = blockIdx.x - 512;
        if (t < 128) cur[t] = runOfs[b * 128 + t];
        __syncthreads();
        const int e0 = b * epb;
        const int e1 = min(e0 + epb, E);
        for (int e = e0 + t; e < e1; e += 512) {
            const unsigned int s = (unsigned int)ei[e];
            const unsigned int d = (unsigned int)ei[E + e];
            const unsigned int p1 = atomicAdd(&cur[s >> 7], 1u);
            edgebuf[p1] = (s << 14) | d;
            const unsigned int p2 = atomicAdd(&cur[d >> 7], 1u);
            edgebuf[p2] = (d << 14) | s;
        }
        return;
    }

    unsigned short* As = smem;
    unsigned short* Bs = smem + 128 * LDAP;

    const int lane = t & 63;
    const int wid = t >> 6;
    const int wr = wid >> 2;
    const int wc = wid & 3;
    const int rowp = blockIdx.x & 127;   // XCD swizzle: 4 colq blocks 128 apart -> same XCD
    const int colq = blockIdx.x >> 7;
    const int row0 = rowp << 7;
    const unsigned short* Wsrc = wb + ((size_t)colq << 15);

    f32x4 acc[4][2] = {};

    for (int k0 = 0; k0 < DD; k0 += BK) {
        uint4 ra_[2], rb_[2];
#pragma unroll
        for (int i = 0; i < 2; ++i) {
            const int f = i * 512 + t;
            const int r = f >> 3, s = f & 7;
            ra_[i] = *(const uint4*)(xb + (size_t)(row0 + r) * DD + k0 + s * 8);
            rb_[i] = *(const uint4*)(Wsrc + (size_t)r * DD + k0 + s * 8);
        }
        __syncthreads();
#pragma unroll
        for (int i = 0; i < 2; ++i) {
            const int f = i * 512 + t;
            const int r = f >> 3, s = f & 7;
            *(uint4*)(&As[r * LDAP + s * 8]) = ra_[i];
            *(uint4*)(&Bs[r * LDAP + s * 8]) = rb_[i];
        }
        __syncthreads();
#pragma unroll
        for (int kk = 0; kk < 2; ++kk) {
            bf16x8 av[4], bv[2];
#pragma unroll
            for (int f = 0; f < 4; ++f) {
                uint4 ra = *(const uint4*)(&As[(wr * 64 + f * 16 + (lane & 15)) * LDAP + kk * 32 + (lane >> 4) * 8]);
                av[f] = __builtin_bit_cast(bf16x8, ra);
            }
#pragma unroll
            for (int f = 0; f < 2; ++f) {
                uint4 rv = *(const uint4*)(&Bs[(wc * 32 + f * 16 + (lane & 15)) * LDAP + kk * 32 + (lane >> 4) * 8]);
                bv[f] = __builtin_bit_cast(bf16x8, rv);
            }
#pragma unroll
            for (int fm = 0; fm < 4; ++fm)
#pragma unroll
                for (int fn = 0; fn < 2; ++fn)
                    acc[fm][fn] = __builtin_amdgcn_mfma_f32_16x16x32_bf16(
                        av[fm], bv[fn], acc[fm][fn], 0, 0, 0);
        }
    }

    const int gr0 = row0 + wr * 64 + ((lane >> 4) << 2);
    const int lc0 = wc * 32 + (lane & 15);
    if (colq < 2) {
        __half* up = xu + (size_t)colq * XUP;
#pragma unroll
        for (int fn = 0; fn < 2; ++fn) {
            const int c = lc0 + fn * 16;          // 0..127 within plane
            const float bias = bu[(colq << 7) + c] + ba[(colq << 7) + c];
#pragma unroll
            for (int fm = 0; fm < 4; ++fm) {
                const int r = gr0 + fm * 16;
#pragma unroll
                for (int i = 0; i < 4; ++i)
                    up[(size_t)(r + i) * 128 + c] = __float2half(acc[fm][fn][i] + bias);
            }
        }
    } else {
        __half* xp = xab + (size_t)(colq - 2) * PLP;
#pragma unroll
        for (int fn = 0; fn < 2; ++fn) {
            const int c = lc0 + fn * 16;
#pragma unroll
            for (int fm = 0; fm < 4; ++fm) {
                const int r = gr0 + fm * 16;
#pragma unroll
                for (int i = 0; i < 4; ++i)
                    xp[(size_t)(r + i) * 128 + c] = __float2half(acc[fm][fn][i]);
            }
        }
    }
}

// ---- K4 fill2: one block per bucket; lists in LDS, sentinel-padded to x32, ---------
//      written out only up to each row's padded count (coalesced 64B groups).
__global__ __launch_bounds__(512) void k_fill2(const unsigned int* __restrict__ edgebuf,
                                               const unsigned int* __restrict__ bstart,
                                               unsigned short* __restrict__ list,
                                               unsigned int* __restrict__ cnt) {
    __shared__ unsigned short ll[128 * CAP];  // 40960 B
    __shared__ unsigned int cur[128];
    const int k = blockIdx.x;
    const int t = threadIdx.x;

    if (t < 128) cur[t] = 0u;
    {
        u16x8 s8;
#pragma unroll
        for (int j = 0; j < 8; ++j) s8[j] = (unsigned short)NN;   // sentinel
        for (int i = t; i < 128 * CAP / 8; i += 512) *(u16x8*)(ll + i * 8) = s8;
    }
    __syncthreads();

    const unsigned int s0 = bstart[k], s1 = bstart[k + 1];
    for (unsigned int j = s0 + t; j < s1; j += 512) {
        const unsigned int e = edgebuf[j];
        const int lr = (int)((e >> 14) & 127u);
        const unsigned short nbr = (unsigned short)(e & 16383u);
        const unsigned int p = atomicAdd(&cur[lr], 1u);
        if (p < CAP) ll[lr * CAP + p] = nbr;
    }
    __syncthreads();

    // 4 threads per row write that row's stripes up to padded count.
    const int lr = t >> 2;       // 0..127
    const int sub = t & 3;
    const unsigned int padded = min((cur[lr] + 31u) & ~31u, (unsigned int)CAP);
    if (sub == 0) cnt[(k << 7) + lr] = padded;
    unsigned short* lrow = list + (size_t)((k << 7) + lr) * CAP;
    for (unsigned int q = sub; q * 8 < padded; q += 4)
        *(u16x8*)(lrow + q * 8) = *(const u16x8*)(ll + lr * CAP + q * 8);
}

// ---- K5/K6: gather pass (per plane) -----------------------------------------------
// 1 wave per row, 4 rows/block. cnt is a multiple of 32 -> only depth-8 main loop.
// Dedup: LDS bitmap; dups & pads -> sentinel row NN (zeros). Epilogue: out =
// xu_plane[row] + acc (pure store -- out is never read).
#define ACC4(S, V) { \
    acc[S][0] = __hadd2(acc[S][0], __builtin_bit_cast(__half2, (V).x)); \
    acc[S][1] = __hadd2(acc[S][1], __builtin_bit_cast(__half2, (V).y)); \
    acc[S][2] = __hadd2(acc[S][2], __builtin_bit_cast(__half2, (V).z)); \
    acc[S][3] = __hadd2(acc[S][3], __builtin_bit_cast(__half2, (V).w)); }

__global__ __launch_bounds__(256) void k_gather(const unsigned int* __restrict__ cnt,
                                                const unsigned short* __restrict__ list,
                                                const __half* __restrict__ plane,
                                                const __half* __restrict__ uplane,
                                                float* __restrict__ out,
                                                int outoff) {
    __shared__ unsigned int bmw[4][512];      // per-wave 2 KiB bitmap
    __shared__ unsigned short lst[4][CAP];

    const int t = threadIdx.x;
    const int wid = t >> 6;
    const int lane = t & 63;
    const int row = (blockIdx.x << 2) + wid;

    uint4 z4; z4.x = 0u; z4.y = 0u; z4.z = 0u; z4.w = 0u;
    ((uint4*)&bmw[wid][0])[lane] = z4;
    ((uint4*)&bmw[wid][0])[64 + lane] = z4;

    const int m = min((int)cnt[row], CAP);
    const unsigned short* gl = list + (size_t)row * CAP;
    for (int i = lane; i < m; i += 64) {
        int idx = gl[i];
        if (idx < NN) {
            const unsigned int bit = 1u << (idx & 31);
            const unsigned int old = atomicOr(&bmw[wid][idx >> 5], bit);
            if (old & bit) idx = NN;          // duplicate -> zero pad row
        }
        lst[wid][i] = (unsigned short)idx;
    }

    const int lg = lane >> 4;      // neighbor-octet slot 0..3
    const int li = lane & 15;      // dim group: f16 dims li*8..li*8+7
    __half2 acc[4][4];
    const __half2 z2 = __float2half2_rn(0.0f);
#pragma unroll
    for (int s = 0; s < 4; ++s) { acc[s][0] = z2; acc[s][1] = z2; acc[s][2] = z2; acc[s][3] = z2; }

    int i = 0;
    for (; i + 32 <= m; i += 32) {
        const u16x8 e = *(const u16x8*)(&lst[wid][i + lg * 8]);  // 1 ds_read_b128
        uint4 v[8];
#pragma unroll
        for (int j = 0; j < 8; ++j)
            v[j] = *(const uint4*)(plane + ((size_t)e[j] << 7) + li * 8);
#pragma unroll
        for (int j = 0; j < 8; ++j) ACC4(j & 3, v[j]);
    }

#pragma unroll
    for (int k = 0; k < 4; ++k) {
        acc[0][k] = __hadd2(acc[0][k], __hadd2(acc[1][k], __hadd2(acc[2][k], acc[3][k])));
        int v = __builtin_bit_cast(int, acc[0][k]);
        v = __shfl_xor(v, 16, 64);
        acc[0][k] = __hadd2(acc[0][k], __builtin_bit_cast(__half2, v));
        v = __builtin_bit_cast(int, acc[0][k]);
        v = __shfl_xor(v, 32, 64);
        acc[0][k] = __hadd2(acc[0][k], __builtin_bit_cast(__half2, v));
    }

    if (lg == 0) {
        const uint4 u = *(const uint4*)(uplane + (size_t)row * 128 + li * 8);
        float4 o0, o1;
        float2 f, g;
        f = __half22float2(acc[0][0]); g = __half22float2(__builtin_bit_cast(__half2, u.x));
        o0.x = f.x + g.x; o0.y = f.y + g.y;
        f = __half22float2(acc[0][1]); g = __half22float2(__builtin_bit_cast(__half2, u.y));
        o0.z = f.x + g.x; o0.w = f.y + g.y;
        f = __half22float2(acc[0][2]); g = __half22float2(__builtin_bit_cast(__half2, u.z));
        o1.x = f.x + g.x; o1.y = f.y + g.y;
        f = __half22float2(acc[0][3]); g = __half22float2(__builtin_bit_cast(__half2, u.w));
        o1.z = f.x + g.x; o1.w = f.y + g.y;
        float4* po = (float4*)(out + (size_t)row * DD + outoff + li * 8);
        po[0] = o0; po[1] = o1;
    }
}

extern "C" void kernel_launch(void* const* d_in, const int* in_sizes, int n_in,
                              void* d_out, int out_size, void* d_ws, size_t ws_size,
                              hipStream_t stream) {
    const float* x  = (const float*)d_in[0];
    const int*   ei = (const int*)d_in[1];
    const float* Wu = (const float*)d_in[2];
    const float* bu = (const float*)d_in[3];
    const float* Wa = (const float*)d_in[4];
    const float* ba = (const float*)d_in[5];
    float* out = (float*)d_out;

    const int E = in_sizes[1] / 2;
    const int epb = (E + NB - 1) / NB;

    char* ws = (char*)d_ws;
    __half* xab = (__half*)ws;                                // 0:        8,396,800 B (2 planes + pads)
    __half* xu = (__half*)(ws + 8396800);                     // 8,396,800: 8,388,608 B (2 planes)
    unsigned short* wb = (unsigned short*)(ws + 16785408);    // 262,144 B bf16 [Wu;Wa]
    unsigned short* xb = (unsigned short*)(ws + 17047552);    // 8,388,608 B bf16 x
    unsigned int* Hc = (unsigned int*)(ws + 25436160);        // 65,536 B
    unsigned int* runOfs = (unsigned int*)(ws + 25501696);    // 65,536 B
    unsigned int* bstart = (unsigned int*)(ws + 25567232);    // 1,024 B
    unsigned int* edgebuf = (unsigned int*)(ws + 25568256);   // 4,194,304 B
    unsigned int* cnt = (unsigned int*)(ws + 29762560);       // 65,536 B
    unsigned short* list = (unsigned short*)(ws + 29828096);  // 5,242,880 B (CAP=160)

    k_prep<<<201, 512, 0, stream>>>(ei, Hc, x, Wu, Wa, xb, wb, xab, E, epb);
    k_scan1<<<1, 512, 0, stream>>>(Hc, runOfs, bstart);
    k_gemm_fill1<<<640, 512, 0, stream>>>(xb, wb, bu, ba, ei, runOfs, edgebuf, xu, xab, E, epb);
    k_fill2<<<NB, 512, 0, stream>>>(edgebuf, bstart, list, cnt);
    k_gather<<<NN / 4, 256, 0, stream>>>(cnt, list, xab, xu, out, 0);
    k_gather<<<NN / 4, 256, 0, stream>>>(cnt, list, xab + PLP, xu + XUP, out, 128);
}